// Round 3
// baseline (1358.879 us; speedup 1.0000x reference)
//
#include <hip/hip_runtime.h>
#include <hip/hip_bf16.h>

#define S 768
#define CS 384
#define CP 128
#define E 16
#define PQ 4
#define PV 8
#define H 12
#define FDIM 2112          // H*(CP+E+PV*4)
#define OFF_PAIR 192       // H*E
#define OFF_PTS 1728       // +H*CP
#define OFF_NORM 2016      // +PV*H*3

typedef __hip_bfloat16 bf16;

__device__ __forceinline__ float b2f(bf16 x){ return __bfloat162float(x); }
__device__ __forceinline__ bf16 f2b(float x){ return __float2bfloat16(x); }
__device__ __forceinline__ float blo(unsigned u){ return __uint_as_float(u << 16); }
__device__ __forceinline__ float bhi(unsigned u){ return __uint_as_float(u & 0xffff0000u); }
__device__ __forceinline__ void up8(uint4 u, float* f){
  f[0]=blo(u.x); f[1]=bhi(u.x); f[2]=blo(u.y); f[3]=bhi(u.y);
  f[4]=blo(u.z); f[5]=bhi(u.z); f[6]=blo(u.w); f[7]=bhi(u.w);
}

// ---------------- kernel 1: projections + frame apply ----------------
// block = one residue s; sr row staged in LDS; 768 flat dot tasks over 256 threads:
//   task 0..191   q[h,e]   192..383 k[h,e]   384..575 v[h,e] -> vT
//   task 576..767 point tasks (h, slot): slot<4 qp, <8 kp, else vp (3 dots + frame)
__global__ __launch_bounds__(256) void k_proj(
    const float* sr, const float* rot, const float* trans,
    const float* Wq, const float* Wk, const float* Wv,
    const float* Wqp, const float* Wkp, const float* Wvp,
    float* q, float* k, float* vT, float* lqp, float* lkp, float* lvpT)
{
  int s = blockIdx.x;
  __shared__ float srs[CS];
  __shared__ float Rs[9];
  __shared__ float ts[3];
  for (int x = threadIdx.x; x < CS; x += 256) srs[x] = sr[(size_t)s*CS + x];
  if (threadIdx.x < 9)  Rs[threadIdx.x] = rot[(size_t)s*9 + threadIdx.x];
  if (threadIdx.x >= 64 && threadIdx.x < 67) ts[threadIdx.x-64] = trans[(size_t)s*3 + threadIdx.x-64];
  __syncthreads();

  for (int task = threadIdx.x; task < 768; task += 256){
    if (task < 576){
      int which = task / 192;
      int he = task - which*192;
      int h = he >> 4, e = he & 15;
      const float* W = (which==0 ? Wq : (which==1 ? Wk : Wv)) + (size_t)he*CS;
      const float4* W4 = (const float4*)W;
      float acc = 0.f;
      for (int cc = 0; cc < CS/4; ++cc){
        float4 w = W4[cc];
        const float* sp = srs + cc*4;
        acc += w.x*sp[0] + w.y*sp[1] + w.z*sp[2] + w.w*sp[3];
      }
      if (which == 0)      q[((size_t)h*S + s)*E + e] = acc;
      else if (which == 1) k[((size_t)h*S + s)*E + e] = acc;
      else                 vT[((size_t)h*E + e)*S + s] = acc;
    } else {
      int pt = task - 576;
      int h = pt >> 4, slot = pt & 15;
      int kind, p; const float* W;
      if (slot < 4)      { kind = 0; p = slot;     W = Wqp + (size_t)((h*PQ+p)*3)*CS; }
      else if (slot < 8) { kind = 1; p = slot - 4; W = Wkp + (size_t)((h*PQ+p)*3)*CS; }
      else               { kind = 2; p = slot - 8; W = Wvp + (size_t)((h*PV+p)*3)*CS; }
      const float4* W0 = (const float4*)W;
      const float4* W1 = (const float4*)(W + CS);
      const float4* W2 = (const float4*)(W + 2*CS);
      float a0 = 0.f, a1 = 0.f, a2 = 0.f;
      for (int cc = 0; cc < CS/4; ++cc){
        float4 w0 = W0[cc], w1 = W1[cc], w2 = W2[cc];
        const float* sp = srs + cc*4;
        a0 += w0.x*sp[0] + w0.y*sp[1] + w0.z*sp[2] + w0.w*sp[3];
        a1 += w1.x*sp[0] + w1.y*sp[1] + w1.z*sp[2] + w1.w*sp[3];
        a2 += w2.x*sp[0] + w2.y*sp[1] + w2.z*sp[2] + w2.w*sp[3];
      }
      float l0 = Rs[0]*a0 + Rs[1]*a1 + Rs[2]*a2 + ts[0];
      float l1 = Rs[3]*a0 + Rs[4]*a1 + Rs[5]*a2 + ts[1];
      float l2 = Rs[6]*a0 + Rs[7]*a1 + Rs[8]*a2 + ts[2];
      if (kind == 0){ float* d = lqp + ((size_t)h*S + s)*12 + p*3; d[0]=l0; d[1]=l1; d[2]=l2; }
      else if (kind == 1){ float* d = lkp + ((size_t)h*S + s)*12 + p*3; d[0]=l0; d[1]=l1; d[2]=l2; }
      else {
        float* dst = lvpT + (size_t)h*24*S;
        dst[(size_t)(p*3+0)*S + s] = l0;
        dst[(size_t)(p*3+1)*S + s] = l1;
        dst[(size_t)(p*3+2)*S + s] = l2;
      }
    }
  }
}

// ---------------- kernel 2a: w_pair logits -> ab (bf16)  ab[h,i,j] = pair[i,j,:].Wb[h,:]
__global__ __launch_bounds__(256) void k_wpair(const float* pair, const float* Wb, bf16* ab)
{
  int i = blockIdx.x;
  int t = threadIdx.x;
  float acc[H][3];
  #pragma unroll
  for (int h = 0; h < H; ++h){ acc[h][0]=0.f; acc[h][1]=0.f; acc[h][2]=0.f; }
  const float4* base = (const float4*)(pair + (size_t)i*S*CP);  // 32 float4 per row of 128
  for (int cc = 0; cc < 32; ++cc){
    float4 pf[3];
    #pragma unroll
    for (int jj = 0; jj < 3; ++jj)
      pf[jj] = base[(size_t)(t + 256*jj)*32 + cc];
    int c0 = cc*4;
    #pragma unroll
    for (int h = 0; h < H; ++h){
      float w0 = Wb[h*CP + c0 + 0];   // block-uniform -> SGPR
      float w1 = Wb[h*CP + c0 + 1];
      float w2 = Wb[h*CP + c0 + 2];
      float w3 = Wb[h*CP + c0 + 3];
      #pragma unroll
      for (int jj = 0; jj < 3; ++jj)
        acc[h][jj] += pf[jj].x*w0 + pf[jj].y*w1 + pf[jj].z*w2 + pf[jj].w*w3;
    }
  }
  #pragma unroll
  for (int h = 0; h < H; ++h){
    size_t base_o = ((size_t)h*S + i)*S + t;
    ab[base_o]       = f2b(acc[h][0]);
    ab[base_o + 256] = f2b(acc[h][1]);
    ab[base_o + 512] = f2b(acc[h][2]);
  }
}

// ---------------- kernel 2b: logits += w_single + w_frame, softmax row -> ab (bf16)
__global__ __launch_bounds__(256) void k_softmax(
    const float* q, const float* k, const float* lqp, const float* lkp,
    const float* gamma, bf16* ab)
{
  int h = blockIdx.x / S, i = blockIdx.x % S;
  int t = threadIdx.x;
  float qs[E], lq[12];
  const float* qrow = q + ((size_t)h*S + i)*E;      // uniform
  #pragma unroll
  for (int e = 0; e < E; ++e) qs[e] = qrow[e];
  const float* lqrow = lqp + ((size_t)h*S + i)*12;  // uniform
  #pragma unroll
  for (int x = 0; x < 12; ++x) lq[x] = lqrow[x];
  float sf = -0.11785113019775793f * log1pf(__expf(gamma[h]));

  size_t base = ((size_t)h*S + i)*S;
  float wv[3];
  #pragma unroll
  for (int jj = 0; jj < 3; ++jj){
    int j = t + jj*256;
    const float* kr = k + ((size_t)h*S + j)*E;
    float d = 0.f;
    #pragma unroll
    for (int e = 0; e < E; ++e) d += qs[e]*kr[e];
    const float* lkr = lkp + ((size_t)h*S + j)*12;
    float fr = 0.f;
    #pragma unroll
    for (int x = 0; x < 12; ++x){ float df = lq[x] - lkr[x]; fr += df*df; }
    wv[jj] = b2f(ab[base + j]) + 0.25f*d + sf*fr;
  }
  __shared__ float red[256];
  float m = fmaxf(fmaxf(wv[0], wv[1]), wv[2]);
  red[t] = m; __syncthreads();
  for (int off = 128; off > 0; off >>= 1){
    if (t < off) red[t] = fmaxf(red[t], red[t+off]);
    __syncthreads();
  }
  m = red[0]; __syncthreads();
  float e0 = __expf(wv[0]-m), e1 = __expf(wv[1]-m), e2 = __expf(wv[2]-m);
  red[t] = e0 + e1 + e2; __syncthreads();
  for (int off = 128; off > 0; off >>= 1){
    if (t < off) red[t] += red[t+off];
    __syncthreads();
  }
  float inv = 1.f/red[0];
  ab[base + t]       = f2b(e0*inv);
  ab[base + t + 256] = f2b(e1*inv);
  ab[base + t + 512] = f2b(e2*inv);
}

// ---------------- kernel 2c: a_sum over queries -> asumT[j*H+h] (fp32, atomic) ----
__global__ __launch_bounds__(256) void k_asum(const bf16* ab, float* asumT)
{
  int h  = blockIdx.x;
  int i0 = blockIdx.y * 96;
  int t  = threadIdx.x;
  float a0 = 0.f, a1 = 0.f, a2 = 0.f;
  for (int i = i0; i < i0 + 96; ++i){
    const bf16* row = ab + ((size_t)h*S + i)*S;
    a0 += b2f(row[t]);
    a1 += b2f(row[t + 256]);
    a2 += b2f(row[t + 512]);
  }
  atomicAdd(&asumT[(t      )*H + h], a0);
  atomicAdd(&asumT[(t + 256)*H + h], a1);
  atomicAdd(&asumT[(t + 512)*H + h], a2);
}

// ---------------- kernel 3: o_single + o_local -> o_global + norms (attn bf16) ----
// block = (h, 4 i's); one wave per i; lanes 0-15: o_single e, 16-39: o_local (p,d)
__global__ __launch_bounds__(256) void k_out_sv(
    const bf16* ab, const float* vT, const float* lvpT,
    const float* rot, const float* trans, bf16* attnb)
{
  int h    = blockIdx.x / (S/4);
  int i0   = (blockIdx.x % (S/4))*4;
  int w    = threadIdx.x >> 6;
  int lane = threadIdx.x & 63;
  int i = i0 + w;
  const uint4* ar4 = (const uint4*)(ab + ((size_t)h*S + i)*S);  // 96 uint4 per row
  float acc = 0.f;
  const float* src = nullptr;
  if (lane < 16)      src = vT   + ((size_t)h*E  + lane)*S;
  else if (lane < 40) src = lvpT + ((size_t)h*24 + (lane-16))*S;
  if (src){
    for (int jb = 0; jb < S/8; ++jb){
      float af[8]; up8(ar4[jb], af);
      float4 s0 = *(const float4*)(src + jb*8);
      float4 s1 = *(const float4*)(src + jb*8 + 4);
      acc += af[0]*s0.x + af[1]*s0.y + af[2]*s0.z + af[3]*s0.w
           + af[4]*s1.x + af[5]*s1.y + af[6]*s1.z + af[7]*s1.w;
    }
  }
  __shared__ float ol[4][24];
  __shared__ float ogs[4][24];
  int pd = lane - 16;
  if (lane >= 16 && lane < 40) ol[w][pd] = acc;
  __syncthreads();
  if (lane < 16){
    attnb[(size_t)i*FDIM + h*E + lane] = f2b(acc);
  } else if (lane < 40){
    int p = pd/3, d = pd%3;
    // o_global_d = sum_j R[j][d]*(o_local_j - t_j)   (Rinv = R^T)
    float r0 = rot[(size_t)i*9 + 0 + d];
    float r1 = rot[(size_t)i*9 + 3 + d];
    float r2 = rot[(size_t)i*9 + 6 + d];
    float x0 = ol[w][p*3+0] - trans[i*3+0];
    float x1 = ol[w][p*3+1] - trans[i*3+1];
    float x2 = ol[w][p*3+2] - trans[i*3+2];
    float og = r0*x0 + r1*x1 + r2*x2;
    attnb[(size_t)i*FDIM + OFF_PTS + p*(H*3) + h*3 + d] = f2b(og);
    ogs[w][pd] = og;
  }
  __syncthreads();
  if (lane >= 16 && lane < 40 && (pd % 3) == 0){
    int p = pd/3;
    float g0 = ogs[w][p*3], g1 = ogs[w][p*3+1], g2 = ogs[w][p*3+2];
    attnb[(size_t)i*FDIM + OFF_NORM + p*H + h] = f2b(sqrtf(g0*g0 + g1*g1 + g2*g2));
  }
}

// ---------------- kernel 4: o_pair[i,h,c] = sum_k asum[h,k]*pair[i,k,c] ----------
__global__ __launch_bounds__(256) void k_opair(const float* pair, const float* asumT, bf16* attnb)
{
  int i = blockIdx.x;
  int t = threadIdx.x;
  int c = t & 127;
  int kg = t >> 7;
  float acc[H];
  #pragma unroll
  for (int h = 0; h < H; ++h) acc[h] = 0.f;
  const float* prow = pair + (size_t)i*S*CP + c;
  for (int kk = 0; kk < S/2; ++kk){
    int kj = kg*(S/2) + kk;
    float pv = prow[(size_t)kj*CP];
    const float* ap = asumT + kj*H;   // uniform per half -> s_loads
    #pragma unroll
    for (int h = 0; h < H; ++h) acc[h] += ap[h]*pv;
  }
  __shared__ float part[2][128][13];  // padded
  #pragma unroll
  for (int h = 0; h < H; ++h) part[kg][c][h] = acc[h];
  __syncthreads();
  if (t < 128){
    #pragma unroll
    for (int h = 0; h < H; ++h)
      attnb[(size_t)i*FDIM + OFF_PAIR + h*CP + t] = f2b(part[0][t][h] + part[1][t][h]);
  }
}

// ---------------- kernel 5: out = attn @ Wo^T + bo (fp32 out) ----------------
__global__ __launch_bounds__(384) void k_final(const bf16* attnb, const float* Wo,
                                               const float* bo, float* out)
{
  int i0 = blockIdx.x*2;
  int o  = threadIdx.x;
  const float4* wrow = (const float4*)(Wo + (size_t)o*FDIM);   // 528 float4
  const unsigned* a0 = (const unsigned*)(attnb + (size_t)i0*FDIM);  // uniform bf16 pairs
  const unsigned* a1 = a0 + FDIM/2;
  float acc0 = 0.f, acc1 = 0.f;
  for (int cc = 0; cc < FDIM/4; ++cc){
    float4 w = wrow[cc];
    unsigned u0 = a0[cc*2], u0b = a0[cc*2+1];
    unsigned u1 = a1[cc*2], u1b = a1[cc*2+1];
    acc0 += w.x*blo(u0) + w.y*bhi(u0) + w.z*blo(u0b) + w.w*bhi(u0b);
    acc1 += w.x*blo(u1) + w.y*bhi(u1) + w.z*blo(u1b) + w.w*bhi(u1b);
  }
  float b = bo[o];
  out[(size_t)i0*CS + o]     = acc0 + b;
  out[(size_t)(i0+1)*CS + o] = acc1 + b;
}

extern "C" void kernel_launch(void* const* d_in, const int* in_sizes, int n_in,
                              void* d_out, int out_size, void* d_ws, size_t ws_size,
                              hipStream_t stream)
{
  const float* sr    = (const float*)d_in[0];
  const float* pair  = (const float*)d_in[1];
  const float* rot   = (const float*)d_in[2];
  const float* trans = (const float*)d_in[3];
  const float* Wq    = (const float*)d_in[4];
  const float* Wk    = (const float*)d_in[5];
  const float* Wv    = (const float*)d_in[6];
  const float* Wqp   = (const float*)d_in[7];
  const float* Wkp   = (const float*)d_in[8];
  const float* Wvp   = (const float*)d_in[9];
  const float* Wb    = (const float*)d_in[10];
  const float* Wo    = (const float*)d_in[11];
  const float* bo    = (const float*)d_in[12];
  const float* gamma = (const float*)d_in[13];

  // workspace layout (float units); total ~5.24M floats = 21 MB
  float* ws    = (float*)d_ws;
  float* q     = ws;                  // 147456
  float* k     = q     + 147456;      // 147456
  float* vT    = k     + 147456;      // 147456 [h][e][s]
  float* lqp   = vT    + 147456;      // 110592
  float* lkp   = lqp   + 110592;      // 110592
  float* lvpT  = lkp   + 110592;      // 221184 [h][pd][s]
  float* asumT = lvpT  + 221184;      // 9216  [j][h]
  bf16*  ab    = (bf16*)(asumT + 9216);              // H*S*S bf16
  bf16*  attnb = (bf16*)(asumT + 9216 + 3538944);    // S*FDIM bf16
  float* out = (float*)d_out;

  hipMemsetAsync(asumT, 0, (size_t)S*H*sizeof(float), stream);
  k_proj   <<<S,           256, 0, stream>>>(sr, rot, trans, Wq, Wk, Wv, Wqp, Wkp, Wvp,
                                             q, k, vT, lqp, lkp, lvpT);
  k_wpair  <<<S,           256, 0, stream>>>(pair, Wb, ab);
  k_softmax<<<H*S,         256, 0, stream>>>(q, k, lqp, lkp, gamma, ab);
  k_asum   <<<dim3(H, 8),  256, 0, stream>>>(ab, asumT);
  k_out_sv <<<H*(S/4),     256, 0, stream>>>(ab, vT, lvpT, rot, trans, attnb);
  k_opair  <<<S,           256, 0, stream>>>(pair, asumT, attnb);
  k_final  <<<S/2,         384, 0, stream>>>(attnb, Wo, bo, out);
}

// Round 4
// 977.790 us; speedup vs baseline: 1.3897x; 1.3897x over previous
//
#include <hip/hip_runtime.h>
#include <hip/hip_bf16.h>

#define S 768
#define CS 384
#define CP 128
#define E 16
#define PQ 4
#define PV 8
#define H 12
#define FDIM 2112          // H*(CP+E+PV*4)
#define OFF_PAIR 192       // H*E
#define OFF_PTS 1728       // +H*CP
#define OFF_NORM 2016      // +PV*H*3

typedef __hip_bfloat16 bf16;

__device__ __forceinline__ float b2f(bf16 x){ return __bfloat162float(x); }
__device__ __forceinline__ bf16 f2b(float x){ return __float2bfloat16(x); }
__device__ __forceinline__ float blo(unsigned u){ return __uint_as_float(u << 16); }
__device__ __forceinline__ float bhi(unsigned u){ return __uint_as_float(u & 0xffff0000u); }
__device__ __forceinline__ void up8(uint4 u, float* f){
  f[0]=blo(u.x); f[1]=bhi(u.x); f[2]=blo(u.y); f[3]=bhi(u.y);
  f[4]=blo(u.z); f[5]=bhi(u.z); f[6]=blo(u.w); f[7]=bhi(u.w);
}

// ---------------- kernel 1: projections + frame apply, 4 residues/block ---------
// 768 tasks strided over 256 threads; each task streams its W row once and
// accumulates 4 residues (W L2 traffic /4 vs 1 residue/block).
__global__ __launch_bounds__(256) void k_proj(
    const float* __restrict__ sr, const float* __restrict__ rot, const float* __restrict__ trans,
    const float* __restrict__ Wq, const float* __restrict__ Wk, const float* __restrict__ Wv,
    const float* __restrict__ Wqp, const float* __restrict__ Wkp, const float* __restrict__ Wvp,
    float* __restrict__ q, float* __restrict__ k, float* __restrict__ vT,
    float* __restrict__ lqp, float* __restrict__ lkp, float* __restrict__ lvpT)
{
  int s0 = blockIdx.x*4;
  __shared__ float srs[4][CS];
  __shared__ float Rs[4][9];
  __shared__ float ts[4][3];
  for (int x = threadIdx.x; x < 4*CS; x += 256) ((float*)srs)[x] = sr[(size_t)s0*CS + x];
  if (threadIdx.x < 36) ((float*)Rs)[threadIdx.x] = rot[(size_t)s0*9 + threadIdx.x];
  if (threadIdx.x >= 64 && threadIdx.x < 76) ((float*)ts)[threadIdx.x-64] = trans[(size_t)s0*3 + threadIdx.x-64];
  __syncthreads();

  for (int task = threadIdx.x; task < 768; task += 256){
    if (task < 576){
      int which = task / 192;
      int he = task - which*192;
      int h = he >> 4, e = he & 15;
      const float* W = (which==0 ? Wq : (which==1 ? Wk : Wv)) + (size_t)he*CS;
      const float4* W4 = (const float4*)W;
      float acc[4] = {0.f,0.f,0.f,0.f};
      for (int cc = 0; cc < CS/4; ++cc){
        float4 w = W4[cc];
        #pragma unroll
        for (int r = 0; r < 4; ++r){
          const float* sp = srs[r] + cc*4;
          acc[r] += w.x*sp[0] + w.y*sp[1] + w.z*sp[2] + w.w*sp[3];
        }
      }
      #pragma unroll
      for (int r = 0; r < 4; ++r){
        int s = s0 + r;
        if (which == 0)      q[((size_t)h*S + s)*E + e] = acc[r];
        else if (which == 1) k[((size_t)h*S + s)*E + e] = acc[r];
        else                 vT[((size_t)h*E + e)*S + s] = acc[r];
      }
    } else {
      int pt = task - 576;
      int h = pt >> 4, slot = pt & 15;
      int kind, p; const float* W;
      if (slot < 4)      { kind = 0; p = slot;     W = Wqp + (size_t)((h*PQ+p)*3)*CS; }
      else if (slot < 8) { kind = 1; p = slot - 4; W = Wkp + (size_t)((h*PQ+p)*3)*CS; }
      else               { kind = 2; p = slot - 8; W = Wvp + (size_t)((h*PV+p)*3)*CS; }
      const float4* W0 = (const float4*)W;
      const float4* W1 = (const float4*)(W + CS);
      const float4* W2 = (const float4*)(W + 2*CS);
      float a0[4] = {0,0,0,0}, a1[4] = {0,0,0,0}, a2[4] = {0,0,0,0};
      for (int cc = 0; cc < CS/4; ++cc){
        float4 w0 = W0[cc], w1 = W1[cc], w2 = W2[cc];
        #pragma unroll
        for (int r = 0; r < 4; ++r){
          const float* sp = srs[r] + cc*4;
          a0[r] += w0.x*sp[0] + w0.y*sp[1] + w0.z*sp[2] + w0.w*sp[3];
          a1[r] += w1.x*sp[0] + w1.y*sp[1] + w1.z*sp[2] + w1.w*sp[3];
          a2[r] += w2.x*sp[0] + w2.y*sp[1] + w2.z*sp[2] + w2.w*sp[3];
        }
      }
      #pragma unroll
      for (int r = 0; r < 4; ++r){
        int s = s0 + r;
        float l0 = Rs[r][0]*a0[r] + Rs[r][1]*a1[r] + Rs[r][2]*a2[r] + ts[r][0];
        float l1 = Rs[r][3]*a0[r] + Rs[r][4]*a1[r] + Rs[r][5]*a2[r] + ts[r][1];
        float l2 = Rs[r][6]*a0[r] + Rs[r][7]*a1[r] + Rs[r][8]*a2[r] + ts[r][2];
        if (kind == 0){ float* d = lqp + ((size_t)h*S + s)*12 + p*3; d[0]=l0; d[1]=l1; d[2]=l2; }
        else if (kind == 1){ float* d = lkp + ((size_t)h*S + s)*12 + p*3; d[0]=l0; d[1]=l1; d[2]=l2; }
        else {
          float* dst = lvpT + (size_t)h*24*S;
          dst[(size_t)(p*3+0)*S + s] = l0;
          dst[(size_t)(p*3+1)*S + s] = l1;
          dst[(size_t)(p*3+2)*S + s] = l2;
        }
      }
    }
  }
}

// ---------------- kernel 2: fused logits (pair+single+frame) + softmax ----------
// block = residue i; thread t owns key rows j = t, t+256, t+512 for ALL 12 heads.
// Pair rows read as back-to-back float4 macro-loads (full 64B lines consumed into
// regs -> no L1-thrash overfetch). Logits in regs; softmax via shfl + tiny LDS.
__global__ __launch_bounds__(256) void k_attn(
    const float* __restrict__ pair, const float* __restrict__ Wb,
    const float* __restrict__ q, const float* __restrict__ k,
    const float* __restrict__ lqp, const float* __restrict__ lkp,
    const float* __restrict__ gamma, bf16* __restrict__ ab)
{
  int i = blockIdx.x;
  int t = threadIdx.x;
  int lane = t & 63;
  int w = t >> 6;

  float wreg[H][3];
  // Phase A: w_pair
  for (int jj = 0; jj < 3; ++jj){
    int j = t + jj*256;
    const float4* prow = (const float4*)(pair + ((size_t)i*S + j)*CP);
    float4 buf[16];
    #pragma unroll
    for (int half = 0; half < 2; ++half){
      #pragma unroll
      for (int cc = 0; cc < 16; ++cc) buf[cc] = prow[half*16 + cc];
      #pragma unroll
      for (int h = 0; h < H; ++h){
        const float4* wb = (const float4*)(Wb + h*CP + half*64);  // uniform -> s_load
        float p0=0.f, p1=0.f, p2=0.f, p3=0.f;
        #pragma unroll
        for (int cc = 0; cc < 16; ++cc){
          float4 wv = wb[cc];
          p0 += wv.x*buf[cc].x; p1 += wv.y*buf[cc].y;
          p2 += wv.z*buf[cc].z; p3 += wv.w*buf[cc].w;
        }
        float v = (p0+p1)+(p2+p3);
        if (half == 0) wreg[h][jj] = v; else wreg[h][jj] += v;
      }
    }
  }

  // Phase B: + w_single + w_frame
  #pragma unroll
  for (int h = 0; h < H; ++h){
    const float* qrow = q   + ((size_t)h*S + i)*E;   // uniform -> s_load
    const float* lqr  = lqp + ((size_t)h*S + i)*12;  // uniform -> s_load
    float sf = -0.11785113019775793f * log1pf(__expf(gamma[h]));
    #pragma unroll
    for (int jj = 0; jj < 3; ++jj){
      int j = t + jj*256;
      const float* kr  = k   + ((size_t)h*S + j)*E;
      const float* lkr = lkp + ((size_t)h*S + j)*12;
      float d = 0.f;
      #pragma unroll
      for (int e = 0; e < E; ++e) d += qrow[e]*kr[e];
      float fr = 0.f;
      #pragma unroll
      for (int x = 0; x < 12; ++x){ float df = lqr[x] - lkr[x]; fr += df*df; }
      wreg[h][jj] += 0.25f*d + sf*fr;
    }
  }

  // Softmax over j (768 values spread: 3 per thread x 256 threads) per head
  __shared__ __align__(16) float redm[H][4];
  __shared__ __align__(16) float redl[H][4];
  float m[H];
  #pragma unroll
  for (int h = 0; h < H; ++h){
    float v = fmaxf(fmaxf(wreg[h][0], wreg[h][1]), wreg[h][2]);
    #pragma unroll
    for (int mk = 1; mk < 64; mk <<= 1) v = fmaxf(v, __shfl_xor(v, mk));
    if (lane == 0) redm[h][w] = v;
  }
  __syncthreads();
  #pragma unroll
  for (int h = 0; h < H; ++h){
    float4 r = *(const float4*)redm[h];
    m[h] = fmaxf(fmaxf(r.x, r.y), fmaxf(r.z, r.w));
  }
  #pragma unroll
  for (int h = 0; h < H; ++h){
    wreg[h][0] = __expf(wreg[h][0] - m[h]);
    wreg[h][1] = __expf(wreg[h][1] - m[h]);
    wreg[h][2] = __expf(wreg[h][2] - m[h]);
    float v = wreg[h][0] + wreg[h][1] + wreg[h][2];
    #pragma unroll
    for (int mk = 1; mk < 64; mk <<= 1) v += __shfl_xor(v, mk);
    if (lane == 0) redl[h][w] = v;
  }
  __syncthreads();
  #pragma unroll
  for (int h = 0; h < H; ++h){
    float4 r = *(const float4*)redl[h];
    float inv = 1.f/((r.x + r.y) + (r.z + r.w));
    size_t base = ((size_t)h*S + i)*S + t;
    ab[base]       = f2b(wreg[h][0]*inv);
    ab[base + 256] = f2b(wreg[h][1]*inv);
    ab[base + 512] = f2b(wreg[h][2]*inv);
  }
}

// ---------------- kernel 3: a_sum over queries -> asumT[j*H+h] (fp32, atomic) ----
__global__ __launch_bounds__(256) void k_asum(const bf16* __restrict__ ab, float* __restrict__ asumT)
{
  int h  = blockIdx.x;
  int i0 = blockIdx.y * 24;
  int t  = threadIdx.x;
  float a0 = 0.f, a1 = 0.f, a2 = 0.f;
  for (int i = i0; i < i0 + 24; ++i){
    const bf16* row = ab + ((size_t)h*S + i)*S;
    a0 += b2f(row[t]);
    a1 += b2f(row[t + 256]);
    a2 += b2f(row[t + 512]);
  }
  atomicAdd(&asumT[(t      )*H + h], a0);
  atomicAdd(&asumT[(t + 256)*H + h], a1);
  atomicAdd(&asumT[(t + 512)*H + h], a2);
}

// ---------------- kernel 4: o_single + o_local -> o_global + norms --------------
__global__ __launch_bounds__(256) void k_out_sv(
    const bf16* __restrict__ ab, const float* __restrict__ vT, const float* __restrict__ lvpT,
    const float* __restrict__ rot, const float* __restrict__ trans, bf16* __restrict__ attnb)
{
  int h    = blockIdx.x / (S/4);
  int i0   = (blockIdx.x % (S/4))*4;
  int w    = threadIdx.x >> 6;
  int lane = threadIdx.x & 63;
  int i = i0 + w;
  const uint4* ar4 = (const uint4*)(ab + ((size_t)h*S + i)*S);  // 96 uint4 per row
  float acc = 0.f;
  const float* src = nullptr;
  if (lane < 16)      src = vT   + ((size_t)h*E  + lane)*S;
  else if (lane < 40) src = lvpT + ((size_t)h*24 + (lane-16))*S;
  if (src){
    for (int jb = 0; jb < S/8; ++jb){
      float af[8]; up8(ar4[jb], af);
      float4 s0 = *(const float4*)(src + jb*8);
      float4 s1 = *(const float4*)(src + jb*8 + 4);
      acc += af[0]*s0.x + af[1]*s0.y + af[2]*s0.z + af[3]*s0.w
           + af[4]*s1.x + af[5]*s1.y + af[6]*s1.z + af[7]*s1.w;
    }
  }
  __shared__ float ol[4][24];
  __shared__ float ogs[4][24];
  int pd = lane - 16;
  if (lane >= 16 && lane < 40) ol[w][pd] = acc;
  __syncthreads();
  if (lane < 16){
    attnb[(size_t)i*FDIM + h*E + lane] = f2b(acc);
  } else if (lane < 40){
    int p = pd/3, d = pd%3;
    float r0 = rot[(size_t)i*9 + 0 + d];
    float r1 = rot[(size_t)i*9 + 3 + d];
    float r2 = rot[(size_t)i*9 + 6 + d];
    float x0 = ol[w][p*3+0] - trans[i*3+0];
    float x1 = ol[w][p*3+1] - trans[i*3+1];
    float x2 = ol[w][p*3+2] - trans[i*3+2];
    float og = r0*x0 + r1*x1 + r2*x2;
    attnb[(size_t)i*FDIM + OFF_PTS + p*(H*3) + h*3 + d] = f2b(og);
    ogs[w][pd] = og;
  }
  __syncthreads();
  if (lane >= 16 && lane < 40 && (pd % 3) == 0){
    int p = pd/3;
    float g0 = ogs[w][p*3], g1 = ogs[w][p*3+1], g2 = ogs[w][p*3+2];
    attnb[(size_t)i*FDIM + OFF_NORM + p*H + h] = f2b(sqrtf(g0*g0 + g1*g1 + g2*g2));
  }
}

// ---------------- kernel 5: o_pair[i,h,c] = sum_k asum[h,k]*pair[i,k,c] ---------
// wave w handles rows kj in [w*192, w*192+192); lanes cover the 128 channels as
// float2 (coalesced 512B/row); asum rows are wave-uniform -> s_load broadcast.
__global__ __launch_bounds__(256) void k_opair(const float* __restrict__ pair,
                                               const float* __restrict__ asumT,
                                               bf16* __restrict__ attnb)
{
  int i  = blockIdx.x;
  int t  = threadIdx.x;
  int c2 = t & 63;
  int g  = __builtin_amdgcn_readfirstlane(t >> 6);   // wave id, uniform
  float accx[H], accy[H];
  #pragma unroll
  for (int h = 0; h < H; ++h){ accx[h] = 0.f; accy[h] = 0.f; }
  const float2* prow = (const float2*)(pair + (size_t)i*S*CP) + c2;
  for (int kk = 0; kk < 192; ++kk){
    int kj = g*192 + kk;
    float2 pv = prow[(size_t)kj*64];
    const float* ap = asumT + kj*H;    // uniform -> s_load
    #pragma unroll
    for (int h = 0; h < H; ++h){
      accx[h] += ap[h]*pv.x;
      accy[h] += ap[h]*pv.y;
    }
  }
  __shared__ float part[4][H][CP];   // 24 KB
  #pragma unroll
  for (int h = 0; h < H; ++h)
    ((float2*)part[g][h])[c2] = make_float2(accx[h], accy[h]);
  __syncthreads();
  if (t < CP){
    #pragma unroll
    for (int h = 0; h < H; ++h){
      float s = part[0][h][t] + part[1][h][t] + part[2][h][t] + part[3][h][t];
      attnb[(size_t)i*FDIM + OFF_PAIR + h*CP + t] = f2b(s);
    }
  }
}

// ---------------- kernel 6: out = attn @ Wo^T + bo (4 rows/block) ---------------
__global__ __launch_bounds__(384) void k_final(const bf16* __restrict__ attnb,
                                               const float* __restrict__ Wo,
                                               const float* __restrict__ bo,
                                               float* __restrict__ out)
{
  int i0 = blockIdx.x*4;
  int o  = threadIdx.x;
  const float4* wrow = (const float4*)(Wo + (size_t)o*FDIM);   // 528 float4
  const unsigned* a0 = (const unsigned*)(attnb + (size_t)i0*FDIM);  // uniform
  const unsigned* a1 = a0 + FDIM/2;
  const unsigned* a2 = a1 + FDIM/2;
  const unsigned* a3 = a2 + FDIM/2;
  float c0=0.f, c1=0.f, c2=0.f, c3=0.f;
  for (int cc = 0; cc < FDIM/4; ++cc){
    float4 wv = wrow[cc];
    unsigned u;
    u = a0[cc*2]; c0 += wv.x*blo(u)+wv.y*bhi(u); u = a0[cc*2+1]; c0 += wv.z*blo(u)+wv.w*bhi(u);
    u = a1[cc*2]; c1 += wv.x*blo(u)+wv.y*bhi(u); u = a1[cc*2+1]; c1 += wv.z*blo(u)+wv.w*bhi(u);
    u = a2[cc*2]; c2 += wv.x*blo(u)+wv.y*bhi(u); u = a2[cc*2+1]; c2 += wv.z*blo(u)+wv.w*bhi(u);
    u = a3[cc*2]; c3 += wv.x*blo(u)+wv.y*bhi(u); u = a3[cc*2+1]; c3 += wv.z*blo(u)+wv.w*bhi(u);
  }
  float b = bo[o];
  out[(size_t)(i0+0)*CS + o] = c0 + b;
  out[(size_t)(i0+1)*CS + o] = c1 + b;
  out[(size_t)(i0+2)*CS + o] = c2 + b;
  out[(size_t)(i0+3)*CS + o] = c3 + b;
}

extern "C" void kernel_launch(void* const* d_in, const int* in_sizes, int n_in,
                              void* d_out, int out_size, void* d_ws, size_t ws_size,
                              hipStream_t stream)
{
  const float* sr    = (const float*)d_in[0];
  const float* pair  = (const float*)d_in[1];
  const float* rot   = (const float*)d_in[2];
  const float* trans = (const float*)d_in[3];
  const float* Wq    = (const float*)d_in[4];
  const float* Wk    = (const float*)d_in[5];
  const float* Wv    = (const float*)d_in[6];
  const float* Wqp   = (const float*)d_in[7];
  const float* Wkp   = (const float*)d_in[8];
  const float* Wvp   = (const float*)d_in[9];
  const float* Wb    = (const float*)d_in[10];
  const float* Wo    = (const float*)d_in[11];
  const float* bo    = (const float*)d_in[12];
  const float* gamma = (const float*)d_in[13];

  // workspace layout (float units); total ~5.24M floats = 21 MB
  float* ws    = (float*)d_ws;
  float* q     = ws;                  // 147456
  float* k     = q     + 147456;      // 147456
  float* vT    = k     + 147456;      // 147456 [h][e][s]
  float* lqp   = vT    + 147456;      // 110592
  float* lkp   = lqp   + 110592;      // 110592
  float* lvpT  = lkp   + 110592;      // 221184 [h][pd][s]
  float* asumT = lvpT  + 221184;      // 9216  [j][h]
  bf16*  ab    = (bf16*)(asumT + 9216);              // H*S*S bf16
  bf16*  attnb = (bf16*)(asumT + 9216 + 3538944);    // S*FDIM bf16
  float* out = (float*)d_out;

  hipMemsetAsync(asumT, 0, (size_t)S*H*sizeof(float), stream);
  k_proj  <<<S/4,          256, 0, stream>>>(sr, rot, trans, Wq, Wk, Wv, Wqp, Wkp, Wvp,
                                             q, k, vT, lqp, lkp, lvpT);
  k_attn  <<<S,            256, 0, stream>>>(pair, Wb, q, k, lqp, lkp, gamma, ab);
  k_asum  <<<dim3(H, 32),  256, 0, stream>>>(ab, asumT);
  k_out_sv<<<H*(S/4),      256, 0, stream>>>(ab, vT, lvpT, rot, trans, attnb);
  k_opair <<<S,            256, 0, stream>>>(pair, asumT, attnb);
  k_final <<<S/4,          384, 0, stream>>>(attnb, Wo, bo, out);
}